// Round 8
// baseline (526.624 us; speedup 1.0000x reference)
//
#include <hip/hip_runtime.h>

// HeteroGraphSAGE on MI355X — fp32 I/O, bf16 MFMA internals.
// R14 (resubmit after GPU acquisition timeout): sage structure frozen at R13
//      (164us, VGPR 80 — compiler already pipelines the gather; ILP saturated,
//      VGPR wall blocks TLP).
//      prep build de-XCD-partitioned: was 8 blocks per edge chunk (each
//      scanning all edges, filtering by node range -> 8x edge re-read,
//      ~128MB). Now single-pass: 1024 blocks = 2 dirs x 512 chunks, every
//      edge read once, unconditional atomicAdd (same 2M atomics, same
//      bucket SETS; per-line serialization unchanged, parallel across lines).
//
// ws layout (bytes):
//   cnt_m @0  cnt_c @256K  bucket_m @1MiB (u32)  bucket_c @14MiB (u16)
//   h_m @27MiB (bf16, +1 zero row)  packed @40MiB (10*32KiB)
//   shadow (ws>=87MiB): xc_bf @41MiB  xm_bf @54MiB  hc_bf @61MiB (each +1 zero row)

typedef unsigned short u16;
typedef unsigned int u32;
typedef short bf16x8 __attribute__((ext_vector_type(8)));
typedef float f32x4 __attribute__((ext_vector_type(4)));
typedef int i32x4 __attribute__((ext_vector_type(4)));
typedef u16 u16x4 __attribute__((ext_vector_type(4)));
typedef u16 u16x8 __attribute__((ext_vector_type(8)));

#define CAP 64
#define LDS_PAD 8
#define ECHUNK 512
#define NBUILD (ECHUNK * 2)          // 1024 (2 dirs x 512 chunks, single pass)
#define NPACK  768                   // 64 x 12

__device__ __forceinline__ float bf2f(u16 u) {
    union { u32 i; float f; } v; v.i = ((u32)u) << 16; return v.f;
}
__device__ __forceinline__ u16 f2bf(float f) {
    union { float f; u32 i; } v; v.f = f;
    u32 i = v.i;
    return (u16)((i + 0x7FFFu + ((i >> 16) & 1u)) >> 16);   // RNE
}
__device__ __forceinline__ bf16x8 cvt8(const float* p) {
    bf16x8 r;
#pragma unroll
    for (int i = 0; i < 8; ++i) r[i] = (short)f2bf(p[i]);
    return r;
}

// ---------------- prep: build + pack + converts in one dispatch ----------------
struct PackDesc { const float* src; u16* dst; int K; int Nsrc; int ntOff; };
struct PrepArgs {
    // build
    const int* src_cm; const int* dst_cm; const int* src_mc; const int* dst_mc;
    int* cnt_m; u32* bucket_m; int* cnt_c; u16* bucket_c;
    int E; int nMerch; int nCard;
    // converts (shadow only; ncBlk/nmBlk = 0 to skip). 4096 elems/block.
    const float* xc; u16* xcb; int ncBlk;
    const float* xm; u16* xmb; int nmBlk;
    // zero-row pointers (shadow only)
    u16* hmz; u16* hcz;
    // pack
    PackDesc pd[12];
};

__global__ void __launch_bounds__(256) prep(PrepArgs a) {
    const int b = blockIdx.x;
    if (b < NBUILD) {
        // ---- bucket build (single-pass, nontemporal edge streams) ----
        const int chunk = b & (ECHUNK - 1);
        const bool dirA = b < ECHUNK;
        const int* dst = dirA ? a.dst_cm : a.dst_mc;
        const int* src = dirA ? a.src_cm : a.src_mc;
        int* cnt = dirA ? a.cnt_m : a.cnt_c;
        const int e0 = (int)((long long)chunk * a.E / ECHUNK);
        const int e1 = (int)((long long)(chunk + 1) * a.E / ECHUNK);
        const int tid = (int)threadIdx.x;

        auto doEdge = [&](int d, int s) {
            int slot = atomicAdd(&cnt[d], 1);
            if (slot < CAP) {
                if (dirA) a.bucket_m[(size_t)d * CAP + slot] = (u32)s;
                else      a.bucket_c[(size_t)d * CAP + slot] = (u16)s;
            }
        };

        int a0 = (e0 + 3) & ~3; if (a0 > e1) a0 = e1;
        int a1 = e1 & ~3;       if (a1 < a0) a1 = a0;
        // scalar head + tail (at most 3 elements each)
        {
            int i = e0 + tid;
            if (i < a0) doEdge(__builtin_nontemporal_load(dst + i),
                               __builtin_nontemporal_load(src + i));
            int t = a1 + tid;
            if (t < e1) doEdge(__builtin_nontemporal_load(dst + t),
                               __builtin_nontemporal_load(src + t));
        }
        // 4-wide vector body: dst+src co-loaded -> 4 independent atomic chains
#pragma unroll 2
        for (int i = a0 + tid * 4; i < a1; i += 1024) {
            i32x4 d4 = __builtin_nontemporal_load(
                reinterpret_cast<const i32x4*>(dst + i));
            i32x4 s4 = __builtin_nontemporal_load(
                reinterpret_cast<const i32x4*>(src + i));
#pragma unroll
            for (int u = 0; u < 4; ++u) doEdge(d4[u], s4[u]);
        }
    } else if (b < NBUILD + NPACK) {
        // ---- weight packing: fp32 W[K,Nsrc] -> bf16 MFMA B fragments ----
        int e = b - NBUILD;
        PackDesc pd = a.pd[e >> 6];
        int idx = (e & 63) * 256 + threadIdx.x;
        int j = idx & 7;
        int lane = (idx >> 3) & 63;
        int t = idx >> 9;
        int nLocal = pd.Nsrc >> 4;
        int ntl = t % nLocal;
        int kt = t / nLocal;
        if (kt >= (pd.K >> 5)) return;
        int k = kt * 32 + ((lane >> 4) << 3) + j;
        int n = ntl * 16 + (lane & 15);
        pd.dst[(((kt * 8 + pd.ntOff + ntl) * 64) + lane) * 8 + j] = f2bf(pd.src[k * pd.Nsrc + n]);
    } else {
        int e = b - NBUILD - NPACK;
        if (e >= a.ncBlk + a.nmBlk) {
            // ---- zero the dummy gather rows (shadow only) ----
            int tid = (int)threadIdx.x;
            if (tid < 64) {
                a.xcb[(size_t)a.nCard  * 64 + tid] = 0;
                a.xmb[(size_t)a.nMerch * 64 + tid] = 0;
            }
            if (tid < 128) {
                a.hmz[tid] = 0;
                a.hcz[tid] = 0;
            }
            return;
        }
        // ---- fp32 -> bf16 shadow converts: 4096 elems / block ----
        const float* s;
        u16* d;
        int n;
        if (e < a.ncBlk) { s = a.xc; d = a.xcb; n = a.nCard * 64; }
        else             { e -= a.ncBlk; s = a.xm; d = a.xmb; n = a.nMerch * 64; }
        int base = e * 4096;
#pragma unroll
        for (int c = 0; c < 4; ++c) {
            int i = base + ((int)threadIdx.x + c * 256) * 4;
            if (i < n) {
                f32x4 v = __builtin_nontemporal_load(
                    reinterpret_cast<const f32x4*>(s + i));
                u16x4 o;
#pragma unroll
                for (int j = 0; j < 4; ++j) o[j] = f2bf(v[j]);
                *reinterpret_cast<u16x4*>(d + i) = o;
            }
        }
    }
}

// ---------------- paired fused SAGE layer (shadow path: all bf16 sources) ----------------
// out = relu(mean_nbr(src) @ Wl + dst @ Wr + bias), N=128. One 16-row tile/wave.
// Zero-row gather: out-of-range lanes/slots load row `zidx` (zeroed in prep) —
// no per-element predication. Gather t-loop is 2-stage software-pipelined
// (prefetch t+8's 4 loads before accumulating t's). All LDS wave-private.
struct SageJob {
    const u16* src;      // bf16 gather source [*, KF] (+1 zero row at zidx)
    const void* adj;     // bucket rows, CAP wide (u32 if idx32 else u16)
    const int* cnt;
    const u16* Wlp;      // packed Wl fragments
    const u16* dst;      // bf16 lin_r source [M, KF]
    const u16* Wrp;
    const float* bias;   // [128]
    float* outF;         // fp32 out [M,128] or null
    u16* outH;           // bf16 out or null
    u16* outS;           // bf16 shadow out or null
    int M;
    int idx32;
    int nBlk;
    int zidx;            // dummy zero-row index in src
    // fused heads (null hW1p = disabled)
    const u16* hW1p;     // packed [cW1 | rW1] fragments, K=128, N=128
    const float* hb1a;   // classifier hidden bias [64]
    const float* hb1b;   // risk hidden bias [64]
    const float* hcW2;   // [64,2]
    const float* hcb2;   // [2]
    const float* hrW2;   // [64]
    const float* hrb2;   // [1]
    float* hpred;        // [M,2]
    float* hrisk;        // [M]
};

template<int KF>
__global__ void __launch_bounds__(256) sage_pair(SageJob j0, SageJob j1) {
    constexpr int NV = KF / 16;    // bf16 elems per lane slice
    __shared__ alignas(16) u16 lds[4][16][KF + LDS_PAD];
    const bool second = (int)blockIdx.x >= j0.nBlk;
    const SageJob& j = second ? j1 : j0;
    const int bx = second ? blockIdx.x - j0.nBlk : blockIdx.x;
    const int lane = threadIdx.x & 63;
    const int wv = threadIdx.x >> 6;
    const int m0 = (bx * 4 + wv) * 16;
    if (m0 >= j.M) return;              // wave-independent; no barriers below
    const int quad = lane >> 4;
    const int l15 = lane & 15;
    const u16* srcH = j.src;
    const u32* adj32 = (const u32*)j.adj;
    const u16* adj16 = (const u16*)j.adj;
    const bool i32 = (j.idx32 != 0);
    const int zidx = j.zidx;

    {
        // one coalesced load covers all 16 row counts
        int cv = j.cnt[m0 + l15];
        // prefetch pair-0 bucket indices
        int ccA_n = min(__shfl(cv, 0), CAP);
        int ccB_n = min(__shfl(cv, 1), CAP);
        int siA_n = zidx, siB_n = zidx;
        if (lane < ccA_n)
            siA_n = i32 ? (int)adj32[(size_t)m0 * CAP + lane]
                        : (int)adj16[(size_t)m0 * CAP + lane];
        if (lane < ccB_n)
            siB_n = i32 ? (int)adj32[(size_t)(m0 + 1) * CAP + lane]
                        : (int)adj16[(size_t)(m0 + 1) * CAP + lane];
        for (int rp = 0; rp < 16; rp += 2) {
            const int ccA = ccA_n, ccB = ccB_n;
            const int siA = siA_n, siB = siB_n;
            const int cfA = __shfl(cv, rp);
            const int cfB = __shfl(cv, rp + 1);
            if (rp < 14) {   // pipeline next pair's index loads behind this pair
                ccA_n = min(__shfl(cv, rp + 2), CAP);
                ccB_n = min(__shfl(cv, rp + 3), CAP);
                siA_n = zidx; siB_n = zidx;
                if (lane < ccA_n)
                    siA_n = i32 ? (int)adj32[(size_t)(m0 + rp + 2) * CAP + lane]
                                : (int)adj16[(size_t)(m0 + rp + 2) * CAP + lane];
                if (lane < ccB_n)
                    siB_n = i32 ? (int)adj32[(size_t)(m0 + rp + 3) * CAP + lane]
                                : (int)adj16[(size_t)(m0 + rp + 3) * CAP + lane];
            }
            float invA = 1.f / (float)max(cfA, 1);
            float invB = 1.f / (float)max(cfB, 1);
            float aA0[NV], aA1[NV], aB0[NV], aB1[NV];
#pragma unroll
            for (int i = 0; i < NV; ++i) { aA0[i] = 0.f; aA1[i] = 0.f; aB0[i] = 0.f; aB1[i] = 0.f; }
            const int cmax = max(ccA, ccB);   // wave-uniform

            // ---- 2-stage pipelined gather: prefetch t+8 before accumulating t ----
            if constexpr (NV == 8) {
                int s0 = __shfl(siA, quad), s1 = __shfl(siA, quad + 4);
                int s2 = __shfl(siB, quad), s3 = __shfl(siB, quad + 4);
                bf16x8 cA0 = *(const bf16x8*)(srcH + (size_t)s0 * KF + l15 * 8);
                bf16x8 cA1 = *(const bf16x8*)(srcH + (size_t)s1 * KF + l15 * 8);
                bf16x8 cB0 = *(const bf16x8*)(srcH + (size_t)s2 * KF + l15 * 8);
                bf16x8 cB1 = *(const bf16x8*)(srcH + (size_t)s3 * KF + l15 * 8);
                int t = 0;
                while (true) {
                    const int tn = t + 8;
                    const bool more = tn < cmax;     // wave-uniform
                    bf16x8 nA0, nA1, nB0, nB1;
                    if (more) {
                        int k0 = tn + quad, k1 = k0 + 4;
                        int x0 = __shfl(siA, k0), x1 = __shfl(siA, k1);
                        int y0 = __shfl(siB, k0), y1 = __shfl(siB, k1);
                        nA0 = *(const bf16x8*)(srcH + (size_t)x0 * KF + l15 * 8);
                        nA1 = *(const bf16x8*)(srcH + (size_t)x1 * KF + l15 * 8);
                        nB0 = *(const bf16x8*)(srcH + (size_t)y0 * KF + l15 * 8);
                        nB1 = *(const bf16x8*)(srcH + (size_t)y1 * KF + l15 * 8);
                    }
#pragma unroll
                    for (int i = 0; i < 8; ++i) {
                        aA0[i] += bf2f((u16)cA0[i]);
                        aA1[i] += bf2f((u16)cA1[i]);
                        aB0[i] += bf2f((u16)cB0[i]);
                        aB1[i] += bf2f((u16)cB1[i]);
                    }
                    if (!more) break;
                    cA0 = nA0; cA1 = nA1; cB0 = nB0; cB1 = nB1;
                    t = tn;
                }
            } else {
                int s0 = __shfl(siA, quad), s1 = __shfl(siA, quad + 4);
                int s2 = __shfl(siB, quad), s3 = __shfl(siB, quad + 4);
                u16x4 cA0 = *(const u16x4*)(srcH + (size_t)s0 * KF + l15 * 4);
                u16x4 cA1 = *(const u16x4*)(srcH + (size_t)s1 * KF + l15 * 4);
                u16x4 cB0 = *(const u16x4*)(srcH + (size_t)s2 * KF + l15 * 4);
                u16x4 cB1 = *(const u16x4*)(srcH + (size_t)s3 * KF + l15 * 4);
                int t = 0;
                while (true) {
                    const int tn = t + 8;
                    const bool more = tn < cmax;
                    u16x4 nA0, nA1, nB0, nB1;
                    if (more) {
                        int k0 = tn + quad, k1 = k0 + 4;
                        int x0 = __shfl(siA, k0), x1 = __shfl(siA, k1);
                        int y0 = __shfl(siB, k0), y1 = __shfl(siB, k1);
                        nA0 = *(const u16x4*)(srcH + (size_t)x0 * KF + l15 * 4);
                        nA1 = *(const u16x4*)(srcH + (size_t)x1 * KF + l15 * 4);
                        nB0 = *(const u16x4*)(srcH + (size_t)y0 * KF + l15 * 4);
                        nB1 = *(const u16x4*)(srcH + (size_t)y1 * KF + l15 * 4);
                    }
#pragma unroll
                    for (int i = 0; i < 4; ++i) {
                        aA0[i] += bf2f(cA0[i]);
                        aA1[i] += bf2f(cA1[i]);
                        aB0[i] += bf2f(cB0[i]);
                        aB1[i] += bf2f(cB1[i]);
                    }
                    if (!more) break;
                    cA0 = nA0; cA1 = nA1; cB0 = nB0; cB1 = nB1;
                    t = tn;
                }
            }

            u16 pkA[NV], pkB[NV];
#pragma unroll
            for (int i = 0; i < NV; ++i) {
                float mA = aA0[i] + aA1[i];
                mA += __shfl_xor(mA, 16);
                mA += __shfl_xor(mA, 32);
                pkA[i] = f2bf(mA * invA);
                float mB = aB0[i] + aB1[i];
                mB += __shfl_xor(mB, 16);
                mB += __shfl_xor(mB, 32);
                pkB[i] = f2bf(mB * invB);
            }
            // post-reduce values are quad-uniform: quad0 -> row rp, quad1 -> row rp+1
            if (quad == 0) {
                if constexpr (NV == 8) *(u16x8*)&lds[wv][rp][l15 * 8] = *(const u16x8*)pkA;
                else                   *(u16x4*)&lds[wv][rp][l15 * 4] = *(const u16x4*)pkA;
            } else if (quad == 1) {
                if constexpr (NV == 8) *(u16x8*)&lds[wv][rp + 1][l15 * 8] = *(const u16x8*)pkB;
                else                   *(u16x4*)&lds[wv][rp + 1][l15 * 4] = *(const u16x4*)pkB;
            }
        }
    }

    // ---------------- MFMA: mean @ Wl + dst @ Wr ----------------
    constexpr int KT = KF >> 5;
    f32x4 acc[8];
#pragma unroll
    for (int i = 0; i < 8; ++i) acc[i] = (f32x4){0.f, 0.f, 0.f, 0.f};

#pragma unroll
    for (int kt = 0; kt < KT; ++kt) {
        bf16x8 av = *reinterpret_cast<const bf16x8*>(&lds[wv][l15][kt * 32 + quad * 8]);
#pragma unroll
        for (int nt = 0; nt < 8; ++nt) {
            bf16x8 bfr = *reinterpret_cast<const bf16x8*>(j.Wlp + (size_t)(((kt * 8 + nt) * 64 + lane) * 8));
            acc[nt] = __builtin_amdgcn_mfma_f32_16x16x32_bf16(av, bfr, acc[nt], 0, 0, 0);
        }
    }
#pragma unroll
    for (int kt = 0; kt < KT; ++kt) {
        bf16x8 av = *reinterpret_cast<const bf16x8*>(j.dst + (size_t)(m0 + l15) * KF + kt * 32 + quad * 8);
#pragma unroll
        for (int nt = 0; nt < 8; ++nt) {
            bf16x8 bfr = *reinterpret_cast<const bf16x8*>(j.Wrp + (size_t)(((kt * 8 + nt) * 64 + lane) * 8));
            acc[nt] = __builtin_amdgcn_mfma_f32_16x16x32_bf16(av, bfr, acc[nt], 0, 0, 0);
        }
    }
    const bool doHead = (j.hW1p != nullptr);
#pragma unroll
    for (int nt = 0; nt < 8; ++nt) {
        int col = nt * 16 + l15;
        float bv = j.bias[col];
#pragma unroll
        for (int r = 0; r < 4; ++r) {
            int row = m0 + quad * 4 + r;
            float v = fmaxf(acc[nt][r] + bv, 0.f);
            u16 hv = f2bf(v);
            if (j.outF) j.outF[(size_t)row * 128 + col] = v;
            if (j.outH) j.outH[(size_t)row * 128 + col] = hv;
            if (j.outS) j.outS[(size_t)row * 128 + col] = hv;
            // stage bf16 h-tile for fused head (wave-private LDS slice)
            if (doHead) lds[wv][quad * 4 + r][col] = hv;
        }
    }
    if (!doHead) return;

    // ---------------- fused heads: hidden = relu(h @ [cW1|rW1] + b1) ----------------
    f32x4 hacc[8];
#pragma unroll
    for (int i = 0; i < 8; ++i) hacc[i] = (f32x4){0.f, 0.f, 0.f, 0.f};
#pragma unroll
    for (int kt = 0; kt < 4; ++kt) {
        bf16x8 av = *reinterpret_cast<const bf16x8*>(&lds[wv][l15][kt * 32 + quad * 8]);
#pragma unroll
        for (int nt = 0; nt < 8; ++nt) {
            bf16x8 bfr = *reinterpret_cast<const bf16x8*>(j.hW1p + (size_t)(((kt * 8 + nt) * 64 + lane) * 8));
            hacc[nt] = __builtin_amdgcn_mfma_f32_16x16x32_bf16(av, bfr, hacc[nt], 0, 0, 0);
        }
    }
    // W2 stage in-register: lane (quad,l15) holds hidden[row=quad*4+r][col=nt*16+l15].
#pragma unroll
    for (int r = 0; r < 4; ++r) {
        float s0 = 0.f, s1 = 0.f, s2 = 0.f;
#pragma unroll
        for (int nt = 0; nt < 4; ++nt) {
            int c = nt * 16 + l15;     // 0..63
            float vc = fmaxf(hacc[nt][r] + j.hb1a[c], 0.f);
            s0 += vc * j.hcW2[c * 2 + 0];
            s1 += vc * j.hcW2[c * 2 + 1];
            float vr = fmaxf(hacc[nt + 4][r] + j.hb1b[c], 0.f);
            s2 += vr * j.hrW2[c];
        }
#pragma unroll
        for (int off = 1; off < 16; off <<= 1) {
            s0 += __shfl_xor(s0, off);
            s1 += __shfl_xor(s1, off);
            s2 += __shfl_xor(s2, off);
        }
        if (l15 == 0) {
            int row = m0 + quad * 4 + r;
            j.hpred[(size_t)row * 2 + 0] = s0 + j.hcb2[0];
            j.hpred[(size_t)row * 2 + 1] = s1 + j.hcb2[1];
            float z = s2 + j.hrb2[0];
            j.hrisk[row] = 1.f / (1.f + __expf(-z));
        }
    }
}

// ---------------- fallback SAGE (fp32 sources, no shadow ws) ----------------
template<typename IdxT, int KF, bool SRCF, bool DSTF, bool OUTF>
__global__ void __launch_bounds__(256) sage_fused(
    const void* __restrict__ Xsrc_, const IdxT* __restrict__ adj,
    const int* __restrict__ cnt,
    const u16* __restrict__ Wlp, const void* __restrict__ Xdst_,
    const u16* __restrict__ Wrp, const float* __restrict__ bias,
    void* __restrict__ out_, int M)
{
    constexpr int NV = KF / 16;
    __shared__ alignas(16) u16 lds[4][16][128 + LDS_PAD];
    const int lane = threadIdx.x & 63;
    const int wv = threadIdx.x >> 6;
    const int m0 = (blockIdx.x * 4 + wv) * 16;
    const bool active = (m0 < M);
    const int quad = lane >> 4;
    const int l15 = lane & 15;

    if (active) {
        const float* srcF = (const float*)Xsrc_;
        const u16*   srcH = (const u16*)Xsrc_;
        for (int r = 0; r < 16; ++r) {
            int node = m0 + r;
            int c = cnt[node];
            int cc = min(c, CAP);
            int sidx = (lane < cc) ? (int)adj[(size_t)node * CAP + lane] : 0;
            float inv = 1.f / (float)max(c, 1);
            float acc0[NV], acc1[NV];
#pragma unroll
            for (int i = 0; i < NV; ++i) { acc0[i] = 0.f; acc1[i] = 0.f; }
            for (int t = 0; t < cc; t += 8) {
                int k0 = t + quad, k1 = t + quad + 4;
                int s0 = __shfl(sidx, k0), s1 = __shfl(sidx, k1);
                bool p0 = k0 < cc, p1 = k1 < cc;
                if constexpr (SRCF) {
                    const f32x4* q0 = (const f32x4*)(srcF + (size_t)s0 * KF + l15 * NV);
                    const f32x4* q1 = (const f32x4*)(srcF + (size_t)s1 * KF + l15 * NV);
                    f32x4 u0 = q0[0], u1 = q1[0];
                    if constexpr (NV == 8) {
                        f32x4 w0 = q0[1], w1 = q1[1];
#pragma unroll
                        for (int i = 0; i < 4; ++i) {
                            acc0[4 + i] += p0 ? w0[i] : 0.f;
                            acc1[4 + i] += p1 ? w1[i] : 0.f;
                        }
                    }
#pragma unroll
                    for (int i = 0; i < 4; ++i) {
                        acc0[i] += p0 ? u0[i] : 0.f;
                        acc1[i] += p1 ? u1[i] : 0.f;
                    }
                } else {
                    if constexpr (NV == 8) {
                        bf16x8 u0 = *(const bf16x8*)(srcH + (size_t)s0 * KF + l15 * 8);
                        bf16x8 u1 = *(const bf16x8*)(srcH + (size_t)s1 * KF + l15 * 8);
#pragma unroll
                        for (int i = 0; i < 8; ++i) {
                            acc0[i] += p0 ? bf2f((u16)u0[i]) : 0.f;
                            acc1[i] += p1 ? bf2f((u16)u1[i]) : 0.f;
                        }
                    } else {
                        u16x4 u0 = *(const u16x4*)(srcH + (size_t)s0 * KF + l15 * 4);
                        u16x4 u1 = *(const u16x4*)(srcH + (size_t)s1 * KF + l15 * 4);
#pragma unroll
                        for (int i = 0; i < 4; ++i) {
                            acc0[i] += p0 ? bf2f(u0[i]) : 0.f;
                            acc1[i] += p1 ? bf2f(u1[i]) : 0.f;
                        }
                    }
                }
            }
            u16 packed[NV];
#pragma unroll
            for (int i = 0; i < NV; ++i) {
                float m = acc0[i] + acc1[i];
                m += __shfl_xor(m, 16);
                m += __shfl_xor(m, 32);
                packed[i] = f2bf(m * inv);
            }
            if (quad == 0) {
                if constexpr (NV == 8) *(u16x8*)&lds[wv][r][l15 * 8] = *(const u16x8*)packed;
                else                   *(u16x4*)&lds[wv][r][l15 * 4] = *(const u16x4*)packed;
            }
        }
    }
    __syncthreads();
    if (!active) return;

    constexpr int KT = KF >> 5;
    f32x4 acc[8];
#pragma unroll
    for (int i = 0; i < 8; ++i) acc[i] = (f32x4){0.f, 0.f, 0.f, 0.f};
#pragma unroll
    for (int kt = 0; kt < KT; ++kt) {
        bf16x8 a = *reinterpret_cast<const bf16x8*>(&lds[wv][l15][kt * 32 + quad * 8]);
#pragma unroll
        for (int nt = 0; nt < 8; ++nt) {
            bf16x8 b = *reinterpret_cast<const bf16x8*>(Wlp + (size_t)(((kt * 8 + nt) * 64 + lane) * 8));
            acc[nt] = __builtin_amdgcn_mfma_f32_16x16x32_bf16(a, b, acc[nt], 0, 0, 0);
        }
    }
#pragma unroll
    for (int kt = 0; kt < KT; ++kt) {
        bf16x8 a;
        if constexpr (DSTF) a = cvt8((const float*)Xdst_ + (size_t)(m0 + l15) * KF + kt * 32 + quad * 8);
        else                a = *reinterpret_cast<const bf16x8*>((const u16*)Xdst_ + (size_t)(m0 + l15) * KF + kt * 32 + quad * 8);
#pragma unroll
        for (int nt = 0; nt < 8; ++nt) {
            bf16x8 b = *reinterpret_cast<const bf16x8*>(Wrp + (size_t)(((kt * 8 + nt) * 64 + lane) * 8));
            acc[nt] = __builtin_amdgcn_mfma_f32_16x16x32_bf16(a, b, acc[nt], 0, 0, 0);
        }
    }
#pragma unroll
    for (int nt = 0; nt < 8; ++nt) {
        int col = nt * 16 + l15;
        float bv = bias[col];
#pragma unroll
        for (int r = 0; r < 4; ++r) {
            int row = m0 + quad * 4 + r;
            float v = fmaxf(acc[nt][r] + bv, 0.f);
            if constexpr (OUTF) ((float*)out_)[(size_t)row * 128 + col] = v;
            else                ((u16*)out_)[(size_t)row * 128 + col] = f2bf(v);
        }
    }
}

// ---------------- paired classifier + risk heads (fallback path only) ----------------
struct HeadJob {
    const float* X; const u16* W1p;
    const float* b1a; const float* b1b;
    const float* cW2; const float* cb2;
    const float* rW2; const float* rb2;
    float* pred; float* risk; int M; int nBlk;
};

__global__ void __launch_bounds__(256) head_pair(HeadJob h0, HeadJob h1) {
    __shared__ alignas(16) u16 lds[4][16][128 + LDS_PAD];
    const bool second = (int)blockIdx.x >= h0.nBlk;
    const HeadJob& h = second ? h1 : h0;
    const int bx = second ? blockIdx.x - h0.nBlk : blockIdx.x;
    const int lane = threadIdx.x & 63;
    const int wv = threadIdx.x >> 6;
    const int m0 = (bx * 4 + wv) * 16;
    const bool active = (m0 < h.M);
    const int quad = lane >> 4;
    const int l15 = lane & 15;

    if (active) {
        f32x4 acc[8];
#pragma unroll
        for (int i = 0; i < 8; ++i) acc[i] = (f32x4){0.f, 0.f, 0.f, 0.f};
#pragma unroll
        for (int kt = 0; kt < 4; ++kt) {
            bf16x8 a = cvt8(h.X + (size_t)(m0 + l15) * 128 + kt * 32 + quad * 8);
#pragma unroll
            for (int nt = 0; nt < 8; ++nt) {
                bf16x8 b = *reinterpret_cast<const bf16x8*>(h.W1p + (size_t)(((kt * 8 + nt) * 64 + lane) * 8));
                acc[nt] = __builtin_amdgcn_mfma_f32_16x16x32_bf16(a, b, acc[nt], 0, 0, 0);
            }
        }
#pragma unroll
        for (int nt = 0; nt < 8; ++nt) {
            int col = nt * 16 + l15;
            float bv = (col < 64) ? h.b1a[col] : h.b1b[col - 64];
#pragma unroll
            for (int r = 0; r < 4; ++r) {
                float v = fmaxf(acc[nt][r] + bv, 0.f);
                lds[wv][quad * 4 + r][col] = f2bf(v);
            }
        }
    }
    __syncthreads();
    if (!active) return;

    float w0 = h.cW2[lane * 2 + 0];
    float w1 = h.cW2[lane * 2 + 1];
    float w2 = h.rW2[lane];
    float cb0 = h.cb2[0], cb1v = h.cb2[1], rb = h.rb2[0];
    for (int r = 0; r < 16; ++r) {
        float t1 = bf2f(lds[wv][r][lane]);
        float t2 = bf2f(lds[wv][r][64 + lane]);
        float s0 = t1 * w0;
        float s1 = t1 * w1;
        float s2 = t2 * w2;
        for (int off = 32; off > 0; off >>= 1) {
            s0 += __shfl_xor(s0, off);
            s1 += __shfl_xor(s1, off);
            s2 += __shfl_xor(s2, off);
        }
        if (lane == 0) {
            int row = m0 + r;
            h.pred[(size_t)row * 2 + 0] = s0 + cb0;
            h.pred[(size_t)row * 2 + 1] = s1 + cb1v;
            float z = s2 + rb;
            h.risk[row] = 1.f / (1.f + __expf(-z));
        }
    }
}

// ---------------- host ----------------
#define OFF_CNT_M  ((size_t)0)
#define OFF_CNT_C  ((size_t)262144)
#define OFF_BKT_M  ((size_t)1  << 20)
#define OFF_BKT_C  ((size_t)14 << 20)
#define OFF_HM     ((size_t)27 << 20)
#define OFF_PACK   ((size_t)40 << 20)
#define OFF_XC     ((size_t)41 << 20)
#define OFF_XM     ((size_t)54 << 20)
#define OFF_HCB    ((size_t)61 << 20)
#define WS_SHADOW_NEED ((size_t)87 << 20)

extern "C" void kernel_launch(void* const* d_in, const int* in_sizes, int n_in,
                              void* d_out, int out_size, void* d_ws, size_t ws_size,
                              hipStream_t stream)
{
    const float* x_card   = (const float*)d_in[0];
    const float* x_merch  = (const float*)d_in[1];
    const int* src_cm     = (const int*)d_in[2];
    const int* dst_cm     = (const int*)d_in[3];
    const int* src_mc     = (const int*)d_in[4];
    const int* dst_mc     = (const int*)d_in[5];
    const float* Wl0_cm   = (const float*)d_in[6];
    const float* bl0_cm   = (const float*)d_in[7];
    const float* Wr0_cm   = (const float*)d_in[8];
    const float* Wl0_mc   = (const float*)d_in[9];
    const float* bl0_mc   = (const float*)d_in[10];
    const float* Wr0_mc   = (const float*)d_in[11];
    const float* Wl1_cm   = (const float*)d_in[12];
    const float* bl1_cm   = (const float*)d_in[13];
    const float* Wr1_cm   = (const float*)d_in[14];
    const float* Wl1_mc   = (const float*)d_in[15];
    const float* bl1_mc   = (const float*)d_in[16];
    const float* Wr1_mc   = (const float*)d_in[17];
    const float* cW1_card = (const float*)d_in[18];
    const float* cb1_card = (const float*)d_in[19];
    const float* cW2_card = (const float*)d_in[20];
    const float* cb2_card = (const float*)d_in[21];
    const float* cW1_mer  = (const float*)d_in[22];
    const float* cb1_mer  = (const float*)d_in[23];
    const float* cW2_mer  = (const float*)d_in[24];
    const float* cb2_mer  = (const float*)d_in[25];
    const float* rW1      = (const float*)d_in[26];
    const float* rb1      = (const float*)d_in[27];
    const float* rW2      = (const float*)d_in[28];
    const float* rb2      = (const float*)d_in[29];

    const int nCard  = in_sizes[0] / 64;   // 100000
    const int nMerch = in_sizes[1] / 64;   // 50000
    const int E      = in_sizes[2];        // 1000000

    char* ws = (char*)d_ws;
    int* cnt_m    = (int*)(ws + OFF_CNT_M);
    int* cnt_c    = (int*)(ws + OFF_CNT_C);
    u32* bucket_m = (u32*)(ws + OFF_BKT_M);
    u16* bucket_c = (u16*)(ws + OFF_BKT_C);
    u16* h_m      = (u16*)(ws + OFF_HM);
    u16* pw       = (u16*)(ws + OFF_PACK);
    u16* pWl0_cm = pw + 0 * 16384;
    u16* pWr0_cm = pw + 1 * 16384;
    u16* pWl0_mc = pw + 2 * 16384;
    u16* pWr0_mc = pw + 3 * 16384;
    u16* pWl1_cm = pw + 4 * 16384;
    u16* pWr1_cm = pw + 5 * 16384;
    u16* pWl1_mc = pw + 6 * 16384;
    u16* pWr1_mc = pw + 7 * 16384;
    u16* pHeadC  = pw + 8 * 16384;
    u16* pHeadM  = pw + 9 * 16384;
    u16* xc_bf   = (u16*)(ws + OFF_XC);
    u16* xm_bf   = (u16*)(ws + OFF_XM);
    u16* hc_bf   = (u16*)(ws + OFF_HCB);

    const bool shadow = (ws_size >= WS_SHADOW_NEED);

    float* out     = (float*)d_out;
    float* o_hc2   = out;
    float* o_hm2   = o_hc2 + (size_t)nCard * 128;
    float* o_predc = o_hm2 + (size_t)nMerch * 128;
    float* o_predm = o_predc + (size_t)nCard * 2;
    float* o_riskc = o_predm + (size_t)nMerch * 2;
    float* o_riskm = o_riskc + (size_t)nCard;

    // zero the count arrays (build uses global atomicAdd)
    hipMemsetAsync(ws, 0, OFF_CNT_C + (size_t)nCard * sizeof(int), stream);

    // ---- prep: build + pack (+ converts + zero-rows when shadow) ----
    PrepArgs pa;
    pa.src_cm = src_cm; pa.dst_cm = dst_cm; pa.src_mc = src_mc; pa.dst_mc = dst_mc;
    pa.cnt_m = cnt_m; pa.bucket_m = bucket_m; pa.cnt_c = cnt_c; pa.bucket_c = bucket_c;
    pa.E = E; pa.nMerch = nMerch; pa.nCard = nCard;
    pa.xc = x_card;  pa.xcb = xc_bf; pa.ncBlk = shadow ? ((nCard * 64 + 4095) / 4096) : 0;   // 1563
    pa.xm = x_merch; pa.xmb = xm_bf; pa.nmBlk = shadow ? ((nMerch * 64 + 4095) / 4096) : 0;  // 782
    pa.hmz = h_m + (size_t)nMerch * 128;
    pa.hcz = hc_bf + (size_t)nCard * 128;
    pa.pd[0]  = { Wl0_cm,   pWl0_cm,  64, 128, 0 };
    pa.pd[1]  = { Wr0_cm,   pWr0_cm,  64, 128, 0 };
    pa.pd[2]  = { Wl0_mc,   pWl0_mc,  64, 128, 0 };
    pa.pd[3]  = { Wr0_mc,   pWr0_mc,  64, 128, 0 };
    pa.pd[4]  = { Wl1_cm,   pWl1_cm, 128, 128, 0 };
    pa.pd[5]  = { Wr1_cm,   pWr1_cm, 128, 128, 0 };
    pa.pd[6]  = { Wl1_mc,   pWl1_mc, 128, 128, 0 };
    pa.pd[7]  = { Wr1_mc,   pWr1_mc, 128, 128, 0 };
    pa.pd[8]  = { cW1_card, pHeadC,  128,  64, 0 };
    pa.pd[9]  = { rW1,      pHeadC,  128,  64, 4 };
    pa.pd[10] = { cW1_mer,  pHeadM,  128,  64, 0 };
    pa.pd[11] = { rW1,      pHeadM,  128,  64, 4 };
    int prepGrid = NBUILD + NPACK + pa.ncBlk + pa.nmBlk + (shadow ? 1 : 0);
    prep<<<prepGrid, 256, 0, stream>>>(pa);

    if (shadow) {
        const int nbM = (nMerch + 63) / 64;   // 782
        const int nbC = (nCard + 63) / 64;    // 1563

        // ---- layer 0 pair (no heads; layer-1 overwrites o_hc2, so no fp32 store) ----
        SageJob a0 = { xc_bf, bucket_m, cnt_m, pWl0_cm, xm_bf, pWr0_cm, bl0_cm,
                       nullptr, h_m, nullptr, nMerch, 1, nbM, nCard,
                       nullptr, nullptr, nullptr, nullptr, nullptr, nullptr, nullptr,
                       nullptr, nullptr };
        SageJob a1 = { xm_bf, bucket_c, cnt_c, pWl0_mc, xc_bf, pWr0_mc, bl0_mc,
                       nullptr, nullptr, hc_bf, nCard, 0, nbC, nMerch,
                       nullptr, nullptr, nullptr, nullptr, nullptr, nullptr, nullptr,
                       nullptr, nullptr };
        sage_pair<64><<<nbM + nbC, 256, 0, stream>>>(a0, a1);

        // ---- layer 1 pair + fused heads ----
        SageJob b0 = { hc_bf, bucket_m, cnt_m, pWl1_cm, h_m, pWr1_cm, bl1_cm,
                       o_hm2, nullptr, nullptr, nMerch, 1, nbM, nCard,
                       pHeadM, cb1_mer, rb1, cW2_mer, cb2_mer, rW2, rb2,
                       o_predm, o_riskm };
        SageJob b1 = { h_m, bucket_c, cnt_c, pWl1_mc, hc_bf, pWr1_mc, bl1_mc,
                       o_hc2, nullptr, nullptr, nCard, 0, nbC, nMerch,
                       pHeadC, cb1_card, rb1, cW2_card, cb2_card, rW2, rb2,
                       o_predc, o_riskc };
        sage_pair<128><<<nbM + nbC, 256, 0, stream>>>(b0, b1);
    } else {
        const int nbM = (nMerch + 63) / 64;   // 782
        const int nbC = (nCard + 63) / 64;    // 1563
        // fallback: fp32 gathers, in-place h_c update (row-disjoint)
        sage_fused<u32, 64, true, true, false><<<nbM, 256, 0, stream>>>(
            x_card, bucket_m, cnt_m, pWl0_cm, x_merch, pWr0_cm, bl0_cm, h_m, nMerch);
        sage_fused<u16, 64, true, true, true><<<nbC, 256, 0, stream>>>(
            x_merch, bucket_c, cnt_c, pWl0_mc, x_card, pWr0_mc, bl0_mc, o_hc2, nCard);
        sage_fused<u32, 128, true, false, true><<<nbM, 256, 0, stream>>>(
            o_hc2, bucket_m, cnt_m, pWl1_cm, h_m, pWr1_cm, bl1_cm, o_hm2, nMerch);
        sage_fused<u16, 128, false, true, true><<<nbC, 256, 0, stream>>>(
            h_m, bucket_c, cnt_c, pWl1_mc, o_hc2, pWr1_mc, bl1_mc, o_hc2, nCard);

        HeadJob hc = { o_hc2, pHeadC, cb1_card, rb1, cW2_card, cb2_card, rW2, rb2,
                       o_predc, o_riskc, nCard, nbC };
        HeadJob hm = { o_hm2, pHeadM, cb1_mer, rb1, cW2_mer, cb2_mer, rW2, rb2,
                       o_predm, o_riskm, nMerch, nbM };
        head_pair<<<nbC + nbM, 256, 0, stream>>>(hc, hm);
    }
}

// Round 9
// 495.681 us; speedup vs baseline: 1.0624x; 1.0624x over previous
//
#include <hip/hip_runtime.h>

// HeteroGraphSAGE on MI355X — fp32 I/O, bf16 MFMA internals.
// R15: R14's single-pass build kept FETCH low (28MB) but prep ROSE to 190us:
//      atomics to 16-counters-per-line arrive from all 8 XCDs -> per-line
//      serialized cross-XCD migrations (VALU 0.9%, occ 84% = all waves parked
//      on atomic round-trips). Fix: pad counters to CSTRIDE=8 ints (32B) —
//      2 nodes/line, ~8x shallower per-line atomic chains. ws repacked tightly
//      (total 88.3MB < proven 91.2MB) so shadow path stays active.
//      Sage structure frozen at R13/R14 (185us, VGPR 80).
//
// ws layout (bytes, tight):
//   cnt_m @0 (1.6M)  cnt_c @1.6M (3.2M)  bucket_m @4.8M (12.8M u32)
//   bucket_c @17.6M (12.8M u16)  h_m @30.4M (12.8M bf16 +zero row)
//   pack @43.20M (320K)  xc_bf @43.53M  xm_bf @56.33M  hc_bf @62.73M
//   end ~88.3M; WS_SHADOW_NEED 89M (< proven 91.2M)

typedef unsigned short u16;
typedef unsigned int u32;
typedef short bf16x8 __attribute__((ext_vector_type(8)));
typedef float f32x4 __attribute__((ext_vector_type(4)));
typedef int i32x4 __attribute__((ext_vector_type(4)));
typedef u16 u16x4 __attribute__((ext_vector_type(4)));
typedef u16 u16x8 __attribute__((ext_vector_type(8)));

#define CAP 64
#define LDS_PAD 8
#define CSTRIDE 8                    // ints per counter slot (32B): 2 nodes/line
#define ECHUNK 512
#define NBUILD (ECHUNK * 2)          // 1024 (2 dirs x 512 chunks, single pass)
#define NPACK  768                   // 64 x 12

__device__ __forceinline__ float bf2f(u16 u) {
    union { u32 i; float f; } v; v.i = ((u32)u) << 16; return v.f;
}
__device__ __forceinline__ u16 f2bf(float f) {
    union { float f; u32 i; } v; v.f = f;
    u32 i = v.i;
    return (u16)((i + 0x7FFFu + ((i >> 16) & 1u)) >> 16);   // RNE
}
__device__ __forceinline__ bf16x8 cvt8(const float* p) {
    bf16x8 r;
#pragma unroll
    for (int i = 0; i < 8; ++i) r[i] = (short)f2bf(p[i]);
    return r;
}

// ---------------- prep: build + pack + converts in one dispatch ----------------
struct PackDesc { const float* src; u16* dst; int K; int Nsrc; int ntOff; };
struct PrepArgs {
    // build
    const int* src_cm; const int* dst_cm; const int* src_mc; const int* dst_mc;
    int* cnt_m; u32* bucket_m; int* cnt_c; u16* bucket_c;
    int E; int nMerch; int nCard;
    // converts (shadow only; ncBlk/nmBlk = 0 to skip). 4096 elems/block.
    const float* xc; u16* xcb; int ncBlk;
    const float* xm; u16* xmb; int nmBlk;
    // zero-row pointers (shadow only)
    u16* hmz; u16* hcz;
    // pack
    PackDesc pd[12];
};

__global__ void __launch_bounds__(256) prep(PrepArgs a) {
    const int b = blockIdx.x;
    if (b < NBUILD) {
        // ---- bucket build (single-pass, padded counters) ----
        const int chunk = b & (ECHUNK - 1);
        const bool dirA = b < ECHUNK;
        const int* dst = dirA ? a.dst_cm : a.dst_mc;
        const int* src = dirA ? a.src_cm : a.src_mc;
        int* cnt = dirA ? a.cnt_m : a.cnt_c;
        const int e0 = (int)((long long)chunk * a.E / ECHUNK);
        const int e1 = (int)((long long)(chunk + 1) * a.E / ECHUNK);
        const int tid = (int)threadIdx.x;

        auto doEdge = [&](int d, int s) {
            int slot = atomicAdd(&cnt[(size_t)d * CSTRIDE], 1);
            if (slot < CAP) {
                if (dirA) a.bucket_m[(size_t)d * CAP + slot] = (u32)s;
                else      a.bucket_c[(size_t)d * CAP + slot] = (u16)s;
            }
        };

        int a0 = (e0 + 3) & ~3; if (a0 > e1) a0 = e1;
        int a1 = e1 & ~3;       if (a1 < a0) a1 = a0;
        // scalar head + tail (at most 3 elements each)
        {
            int i = e0 + tid;
            if (i < a0) doEdge(__builtin_nontemporal_load(dst + i),
                               __builtin_nontemporal_load(src + i));
            int t = a1 + tid;
            if (t < e1) doEdge(__builtin_nontemporal_load(dst + t),
                               __builtin_nontemporal_load(src + t));
        }
        // 4-wide vector body: dst+src co-loaded -> 4 independent atomic chains
#pragma unroll 2
        for (int i = a0 + tid * 4; i < a1; i += 1024) {
            i32x4 d4 = __builtin_nontemporal_load(
                reinterpret_cast<const i32x4*>(dst + i));
            i32x4 s4 = __builtin_nontemporal_load(
                reinterpret_cast<const i32x4*>(src + i));
#pragma unroll
            for (int u = 0; u < 4; ++u) doEdge(d4[u], s4[u]);
        }
    } else if (b < NBUILD + NPACK) {
        // ---- weight packing: fp32 W[K,Nsrc] -> bf16 MFMA B fragments ----
        int e = b - NBUILD;
        PackDesc pd = a.pd[e >> 6];
        int idx = (e & 63) * 256 + threadIdx.x;
        int j = idx & 7;
        int lane = (idx >> 3) & 63;
        int t = idx >> 9;
        int nLocal = pd.Nsrc >> 4;
        int ntl = t % nLocal;
        int kt = t / nLocal;
        if (kt >= (pd.K >> 5)) return;
        int k = kt * 32 + ((lane >> 4) << 3) + j;
        int n = ntl * 16 + (lane & 15);
        pd.dst[(((kt * 8 + pd.ntOff + ntl) * 64) + lane) * 8 + j] = f2bf(pd.src[k * pd.Nsrc + n]);
    } else {
        int e = b - NBUILD - NPACK;
        if (e >= a.ncBlk + a.nmBlk) {
            // ---- zero the dummy gather rows (shadow only) ----
            int tid = (int)threadIdx.x;
            if (tid < 64) {
                a.xcb[(size_t)a.nCard  * 64 + tid] = 0;
                a.xmb[(size_t)a.nMerch * 64 + tid] = 0;
            }
            if (tid < 128) {
                a.hmz[tid] = 0;
                a.hcz[tid] = 0;
            }
            return;
        }
        // ---- fp32 -> bf16 shadow converts: 4096 elems / block ----
        const float* s;
        u16* d;
        int n;
        if (e < a.ncBlk) { s = a.xc; d = a.xcb; n = a.nCard * 64; }
        else             { e -= a.ncBlk; s = a.xm; d = a.xmb; n = a.nMerch * 64; }
        int base = e * 4096;
#pragma unroll
        for (int c = 0; c < 4; ++c) {
            int i = base + ((int)threadIdx.x + c * 256) * 4;
            if (i < n) {
                f32x4 v = __builtin_nontemporal_load(
                    reinterpret_cast<const f32x4*>(s + i));
                u16x4 o;
#pragma unroll
                for (int j = 0; j < 4; ++j) o[j] = f2bf(v[j]);
                *reinterpret_cast<u16x4*>(d + i) = o;
            }
        }
    }
}

// ---------------- paired fused SAGE layer (shadow path: all bf16 sources) ----------------
// out = relu(mean_nbr(src) @ Wl + dst @ Wr + bias), N=128. One 16-row tile/wave.
// Zero-row gather: out-of-range lanes/slots load row `zidx` (zeroed in prep) —
// no per-element predication. Gather t-loop is 2-stage software-pipelined
// (prefetch t+8's 4 loads before accumulating t's). All LDS wave-private.
struct SageJob {
    const u16* src;      // bf16 gather source [*, KF] (+1 zero row at zidx)
    const void* adj;     // bucket rows, CAP wide (u32 if idx32 else u16)
    const int* cnt;      // padded: node i at cnt[i*CSTRIDE]
    const u16* Wlp;      // packed Wl fragments
    const u16* dst;      // bf16 lin_r source [M, KF]
    const u16* Wrp;
    const float* bias;   // [128]
    float* outF;         // fp32 out [M,128] or null
    u16* outH;           // bf16 out or null
    u16* outS;           // bf16 shadow out or null
    int M;
    int idx32;
    int nBlk;
    int zidx;            // dummy zero-row index in src
    // fused heads (null hW1p = disabled)
    const u16* hW1p;     // packed [cW1 | rW1] fragments, K=128, N=128
    const float* hb1a;   // classifier hidden bias [64]
    const float* hb1b;   // risk hidden bias [64]
    const float* hcW2;   // [64,2]
    const float* hcb2;   // [2]
    const float* hrW2;   // [64]
    const float* hrb2;   // [1]
    float* hpred;        // [M,2]
    float* hrisk;        // [M]
};

template<int KF>
__global__ void __launch_bounds__(256) sage_pair(SageJob j0, SageJob j1) {
    constexpr int NV = KF / 16;    // bf16 elems per lane slice
    __shared__ alignas(16) u16 lds[4][16][KF + LDS_PAD];
    const bool second = (int)blockIdx.x >= j0.nBlk;
    const SageJob& j = second ? j1 : j0;
    const int bx = second ? blockIdx.x - j0.nBlk : blockIdx.x;
    const int lane = threadIdx.x & 63;
    const int wv = threadIdx.x >> 6;
    const int m0 = (bx * 4 + wv) * 16;
    if (m0 >= j.M) return;              // wave-independent; no barriers below
    const int quad = lane >> 4;
    const int l15 = lane & 15;
    const u16* srcH = j.src;
    const u32* adj32 = (const u32*)j.adj;
    const u16* adj16 = (const u16*)j.adj;
    const bool i32 = (j.idx32 != 0);
    const int zidx = j.zidx;

    {
        // 16 row counts (padded stride; one strided load per tile)
        int cv = j.cnt[(size_t)(m0 + l15) * CSTRIDE];
        // prefetch pair-0 bucket indices
        int ccA_n = min(__shfl(cv, 0), CAP);
        int ccB_n = min(__shfl(cv, 1), CAP);
        int siA_n = zidx, siB_n = zidx;
        if (lane < ccA_n)
            siA_n = i32 ? (int)adj32[(size_t)m0 * CAP + lane]
                        : (int)adj16[(size_t)m0 * CAP + lane];
        if (lane < ccB_n)
            siB_n = i32 ? (int)adj32[(size_t)(m0 + 1) * CAP + lane]
                        : (int)adj16[(size_t)(m0 + 1) * CAP + lane];
        for (int rp = 0; rp < 16; rp += 2) {
            const int ccA = ccA_n, ccB = ccB_n;
            const int siA = siA_n, siB = siB_n;
            const int cfA = __shfl(cv, rp);
            const int cfB = __shfl(cv, rp + 1);
            if (rp < 14) {   // pipeline next pair's index loads behind this pair
                ccA_n = min(__shfl(cv, rp + 2), CAP);
                ccB_n = min(__shfl(cv, rp + 3), CAP);
                siA_n = zidx; siB_n = zidx;
                if (lane < ccA_n)
                    siA_n = i32 ? (int)adj32[(size_t)(m0 + rp + 2) * CAP + lane]
                                : (int)adj16[(size_t)(m0 + rp + 2) * CAP + lane];
                if (lane < ccB_n)
                    siB_n = i32 ? (int)adj32[(size_t)(m0 + rp + 3) * CAP + lane]
                                : (int)adj16[(size_t)(m0 + rp + 3) * CAP + lane];
            }
            float invA = 1.f / (float)max(cfA, 1);
            float invB = 1.f / (float)max(cfB, 1);
            float aA0[NV], aA1[NV], aB0[NV], aB1[NV];
#pragma unroll
            for (int i = 0; i < NV; ++i) { aA0[i] = 0.f; aA1[i] = 0.f; aB0[i] = 0.f; aB1[i] = 0.f; }
            const int cmax = max(ccA, ccB);   // wave-uniform

            // ---- 2-stage pipelined gather: prefetch t+8 before accumulating t ----
            if constexpr (NV == 8) {
                int s0 = __shfl(siA, quad), s1 = __shfl(siA, quad + 4);
                int s2 = __shfl(siB, quad), s3 = __shfl(siB, quad + 4);
                bf16x8 cA0 = *(const bf16x8*)(srcH + (size_t)s0 * KF + l15 * 8);
                bf16x8 cA1 = *(const bf16x8*)(srcH + (size_t)s1 * KF + l15 * 8);
                bf16x8 cB0 = *(const bf16x8*)(srcH + (size_t)s2 * KF + l15 * 8);
                bf16x8 cB1 = *(const bf16x8*)(srcH + (size_t)s3 * KF + l15 * 8);
                int t = 0;
                while (true) {
                    const int tn = t + 8;
                    const bool more = tn < cmax;     // wave-uniform
                    bf16x8 nA0, nA1, nB0, nB1;
                    if (more) {
                        int k0 = tn + quad, k1 = k0 + 4;
                        int x0 = __shfl(siA, k0), x1 = __shfl(siA, k1);
                        int y0 = __shfl(siB, k0), y1 = __shfl(siB, k1);
                        nA0 = *(const bf16x8*)(srcH + (size_t)x0 * KF + l15 * 8);
                        nA1 = *(const bf16x8*)(srcH + (size_t)x1 * KF + l15 * 8);
                        nB0 = *(const bf16x8*)(srcH + (size_t)y0 * KF + l15 * 8);
                        nB1 = *(const bf16x8*)(srcH + (size_t)y1 * KF + l15 * 8);
                    }
#pragma unroll
                    for (int i = 0; i < 8; ++i) {
                        aA0[i] += bf2f((u16)cA0[i]);
                        aA1[i] += bf2f((u16)cA1[i]);
                        aB0[i] += bf2f((u16)cB0[i]);
                        aB1[i] += bf2f((u16)cB1[i]);
                    }
                    if (!more) break;
                    cA0 = nA0; cA1 = nA1; cB0 = nB0; cB1 = nB1;
                    t = tn;
                }
            } else {
                int s0 = __shfl(siA, quad), s1 = __shfl(siA, quad + 4);
                int s2 = __shfl(siB, quad), s3 = __shfl(siB, quad + 4);
                u16x4 cA0 = *(const u16x4*)(srcH + (size_t)s0 * KF + l15 * 4);
                u16x4 cA1 = *(const u16x4*)(srcH + (size_t)s1 * KF + l15 * 4);
                u16x4 cB0 = *(const u16x4*)(srcH + (size_t)s2 * KF + l15 * 4);
                u16x4 cB1 = *(const u16x4*)(srcH + (size_t)s3 * KF + l15 * 4);
                int t = 0;
                while (true) {
                    const int tn = t + 8;
                    const bool more = tn < cmax;
                    u16x4 nA0, nA1, nB0, nB1;
                    if (more) {
                        int k0 = tn + quad, k1 = k0 + 4;
                        int x0 = __shfl(siA, k0), x1 = __shfl(siA, k1);
                        int y0 = __shfl(siB, k0), y1 = __shfl(siB, k1);
                        nA0 = *(const u16x4*)(srcH + (size_t)x0 * KF + l15 * 4);
                        nA1 = *(const u16x4*)(srcH + (size_t)x1 * KF + l15 * 4);
                        nB0 = *(const u16x4*)(srcH + (size_t)y0 * KF + l15 * 4);
                        nB1 = *(const u16x4*)(srcH + (size_t)y1 * KF + l15 * 4);
                    }
#pragma unroll
                    for (int i = 0; i < 4; ++i) {
                        aA0[i] += bf2f(cA0[i]);
                        aA1[i] += bf2f(cA1[i]);
                        aB0[i] += bf2f(cB0[i]);
                        aB1[i] += bf2f(cB1[i]);
                    }
                    if (!more) break;
                    cA0 = nA0; cA1 = nA1; cB0 = nB0; cB1 = nB1;
                    t = tn;
                }
            }

            u16 pkA[NV], pkB[NV];
#pragma unroll
            for (int i = 0; i < NV; ++i) {
                float mA = aA0[i] + aA1[i];
                mA += __shfl_xor(mA, 16);
                mA += __shfl_xor(mA, 32);
                pkA[i] = f2bf(mA * invA);
                float mB = aB0[i] + aB1[i];
                mB += __shfl_xor(mB, 16);
                mB += __shfl_xor(mB, 32);
                pkB[i] = f2bf(mB * invB);
            }
            // post-reduce values are quad-uniform: quad0 -> row rp, quad1 -> row rp+1
            if (quad == 0) {
                if constexpr (NV == 8) *(u16x8*)&lds[wv][rp][l15 * 8] = *(const u16x8*)pkA;
                else                   *(u16x4*)&lds[wv][rp][l15 * 4] = *(const u16x4*)pkA;
            } else if (quad == 1) {
                if constexpr (NV == 8) *(u16x8*)&lds[wv][rp + 1][l15 * 8] = *(const u16x8*)pkB;
                else                   *(u16x4*)&lds[wv][rp + 1][l15 * 4] = *(const u16x4*)pkB;
            }
        }
    }

    // ---------------- MFMA: mean @ Wl + dst @ Wr ----------------
    constexpr int KT = KF >> 5;
    f32x4 acc[8];
#pragma unroll
    for (int i = 0; i < 8; ++i) acc[i] = (f32x4){0.f, 0.f, 0.f, 0.f};

#pragma unroll
    for (int kt = 0; kt < KT; ++kt) {
        bf16x8 av = *reinterpret_cast<const bf16x8*>(&lds[wv][l15][kt * 32 + quad * 8]);
#pragma unroll
        for (int nt = 0; nt < 8; ++nt) {
            bf16x8 bfr = *reinterpret_cast<const bf16x8*>(j.Wlp + (size_t)(((kt * 8 + nt) * 64 + lane) * 8));
            acc[nt] = __builtin_amdgcn_mfma_f32_16x16x32_bf16(av, bfr, acc[nt], 0, 0, 0);
        }
    }
#pragma unroll
    for (int kt = 0; kt < KT; ++kt) {
        bf16x8 av = *reinterpret_cast<const bf16x8*>(j.dst + (size_t)(m0 + l15) * KF + kt * 32 + quad * 8);
#pragma unroll
        for (int nt = 0; nt < 8; ++nt) {
            bf16x8 bfr = *reinterpret_cast<const bf16x8*>(j.Wrp + (size_t)(((kt * 8 + nt) * 64 + lane) * 8));
            acc[nt] = __builtin_amdgcn_mfma_f32_16x16x32_bf16(av, bfr, acc[nt], 0, 0, 0);
        }
    }
    const bool doHead = (j.hW1p != nullptr);
#pragma unroll
    for (int nt = 0; nt < 8; ++nt) {
        int col = nt * 16 + l15;
        float bv = j.bias[col];
#pragma unroll
        for (int r = 0; r < 4; ++r) {
            int row = m0 + quad * 4 + r;
            float v = fmaxf(acc[nt][r] + bv, 0.f);
            u16 hv = f2bf(v);
            if (j.outF) j.outF[(size_t)row * 128 + col] = v;
            if (j.outH) j.outH[(size_t)row * 128 + col] = hv;
            if (j.outS) j.outS[(size_t)row * 128 + col] = hv;
            // stage bf16 h-tile for fused head (wave-private LDS slice)
            if (doHead) lds[wv][quad * 4 + r][col] = hv;
        }
    }
    if (!doHead) return;

    // ---------------- fused heads: hidden = relu(h @ [cW1|rW1] + b1) ----------------
    f32x4 hacc[8];
#pragma unroll
    for (int i = 0; i < 8; ++i) hacc[i] = (f32x4){0.f, 0.f, 0.f, 0.f};
#pragma unroll
    for (int kt = 0; kt < 4; ++kt) {
        bf16x8 av = *reinterpret_cast<const bf16x8*>(&lds[wv][l15][kt * 32 + quad * 8]);
#pragma unroll
        for (int nt = 0; nt < 8; ++nt) {
            bf16x8 bfr = *reinterpret_cast<const bf16x8*>(j.hW1p + (size_t)(((kt * 8 + nt) * 64 + lane) * 8));
            hacc[nt] = __builtin_amdgcn_mfma_f32_16x16x32_bf16(av, bfr, hacc[nt], 0, 0, 0);
        }
    }
    // W2 stage in-register: lane (quad,l15) holds hidden[row=quad*4+r][col=nt*16+l15].
#pragma unroll
    for (int r = 0; r < 4; ++r) {
        float s0 = 0.f, s1 = 0.f, s2 = 0.f;
#pragma unroll
        for (int nt = 0; nt < 4; ++nt) {
            int c = nt * 16 + l15;     // 0..63
            float vc = fmaxf(hacc[nt][r] + j.hb1a[c], 0.f);
            s0 += vc * j.hcW2[c * 2 + 0];
            s1 += vc * j.hcW2[c * 2 + 1];
            float vr = fmaxf(hacc[nt + 4][r] + j.hb1b[c], 0.f);
            s2 += vr * j.hrW2[c];
        }
#pragma unroll
        for (int off = 1; off < 16; off <<= 1) {
            s0 += __shfl_xor(s0, off);
            s1 += __shfl_xor(s1, off);
            s2 += __shfl_xor(s2, off);
        }
        if (l15 == 0) {
            int row = m0 + quad * 4 + r;
            j.hpred[(size_t)row * 2 + 0] = s0 + j.hcb2[0];
            j.hpred[(size_t)row * 2 + 1] = s1 + j.hcb2[1];
            float z = s2 + j.hrb2[0];
            j.hrisk[row] = 1.f / (1.f + __expf(-z));
        }
    }
}

// ---------------- fallback SAGE (fp32 sources, no shadow ws) ----------------
template<typename IdxT, int KF, bool SRCF, bool DSTF, bool OUTF>
__global__ void __launch_bounds__(256) sage_fused(
    const void* __restrict__ Xsrc_, const IdxT* __restrict__ adj,
    const int* __restrict__ cnt,
    const u16* __restrict__ Wlp, const void* __restrict__ Xdst_,
    const u16* __restrict__ Wrp, const float* __restrict__ bias,
    void* __restrict__ out_, int M)
{
    constexpr int NV = KF / 16;
    __shared__ alignas(16) u16 lds[4][16][128 + LDS_PAD];
    const int lane = threadIdx.x & 63;
    const int wv = threadIdx.x >> 6;
    const int m0 = (blockIdx.x * 4 + wv) * 16;
    const bool active = (m0 < M);
    const int quad = lane >> 4;
    const int l15 = lane & 15;

    if (active) {
        const float* srcF = (const float*)Xsrc_;
        const u16*   srcH = (const u16*)Xsrc_;
        for (int r = 0; r < 16; ++r) {
            int node = m0 + r;
            int c = cnt[(size_t)node * CSTRIDE];
            int cc = min(c, CAP);
            int sidx = (lane < cc) ? (int)adj[(size_t)node * CAP + lane] : 0;
            float inv = 1.f / (float)max(c, 1);
            float acc0[NV], acc1[NV];
#pragma unroll
            for (int i = 0; i < NV; ++i) { acc0[i] = 0.f; acc1[i] = 0.f; }
            for (int t = 0; t < cc; t += 8) {
                int k0 = t + quad, k1 = t + quad + 4;
                int s0 = __shfl(sidx, k0), s1 = __shfl(sidx, k1);
                bool p0 = k0 < cc, p1 = k1 < cc;
                if constexpr (SRCF) {
                    const f32x4* q0 = (const f32x4*)(srcF + (size_t)s0 * KF + l15 * NV);
                    const f32x4* q1 = (const f32x4*)(srcF + (size_t)s1 * KF + l15 * NV);
                    f32x4 u0 = q0[0], u1 = q1[0];
                    if constexpr (NV == 8) {
                        f32x4 w0 = q0[1], w1 = q1[1];
#pragma unroll
                        for (int i = 0; i < 4; ++i) {
                            acc0[4 + i] += p0 ? w0[i] : 0.f;
                            acc1[4 + i] += p1 ? w1[i] : 0.f;
                        }
                    }
#pragma unroll
                    for (int i = 0; i < 4; ++i) {
                        acc0[i] += p0 ? u0[i] : 0.f;
                        acc1[i] += p1 ? u1[i] : 0.f;
                    }
                } else {
                    if constexpr (NV == 8) {
                        bf16x8 u0 = *(const bf16x8*)(srcH + (size_t)s0 * KF + l15 * 8);
                        bf16x8 u1 = *(const bf16x8*)(srcH + (size_t)s1 * KF + l15 * 8);
#pragma unroll
                        for (int i = 0; i < 8; ++i) {
                            acc0[i] += p0 ? bf2f((u16)u0[i]) : 0.f;
                            acc1[i] += p1 ? bf2f((u16)u1[i]) : 0.f;
                        }
                    } else {
                        u16x4 u0 = *(const u16x4*)(srcH + (size_t)s0 * KF + l15 * 4);
                        u16x4 u1 = *(const u16x4*)(srcH + (size_t)s1 * KF + l15 * 4);
#pragma unroll
                        for (int i = 0; i < 4; ++i) {
                            acc0[i] += p0 ? bf2f(u0[i]) : 0.f;
                            acc1[i] += p1 ? bf2f(u1[i]) : 0.f;
                        }
                    }
                }
            }
            u16 packed[NV];
#pragma unroll
            for (int i = 0; i < NV; ++i) {
                float m = acc0[i] + acc1[i];
                m += __shfl_xor(m, 16);
                m += __shfl_xor(m, 32);
                packed[i] = f2bf(m * inv);
            }
            if (quad == 0) {
                if constexpr (NV == 8) *(u16x8*)&lds[wv][r][l15 * 8] = *(const u16x8*)packed;
                else                   *(u16x4*)&lds[wv][r][l15 * 4] = *(const u16x4*)packed;
            }
        }
    }
    __syncthreads();
    if (!active) return;

    constexpr int KT = KF >> 5;
    f32x4 acc[8];
#pragma unroll
    for (int i = 0; i < 8; ++i) acc[i] = (f32x4){0.f, 0.f, 0.f, 0.f};
#pragma unroll
    for (int kt = 0; kt < KT; ++kt) {
        bf16x8 a = *reinterpret_cast<const bf16x8*>(&lds[wv][l15][kt * 32 + quad * 8]);
#pragma unroll
        for (int nt = 0; nt < 8; ++nt) {
            bf16x8 b = *reinterpret_cast<const bf16x8*>(Wlp + (size_t)(((kt * 8 + nt) * 64 + lane) * 8));
            acc[nt] = __builtin_amdgcn_mfma_f32_16x16x32_bf16(a, b, acc[nt], 0, 0, 0);
        }
    }
#pragma unroll
    for (int kt = 0; kt < KT; ++kt) {
        bf16x8 a;
        if constexpr (DSTF) a = cvt8((const float*)Xdst_ + (size_t)(m0 + l15) * KF + kt * 32 + quad * 8);
        else                a = *reinterpret_cast<const bf16x8*>((const u16*)Xdst_ + (size_t)(m0 + l15) * KF + kt * 32 + quad * 8);
#pragma unroll
        for (int nt = 0; nt < 8; ++nt) {
            bf16x8 b = *reinterpret_cast<const bf16x8*>(Wrp + (size_t)(((kt * 8 + nt) * 64 + lane) * 8));
            acc[nt] = __builtin_amdgcn_mfma_f32_16x16x32_bf16(a, b, acc[nt], 0, 0, 0);
        }
    }
#pragma unroll
    for (int nt = 0; nt < 8; ++nt) {
        int col = nt * 16 + l15;
        float bv = bias[col];
#pragma unroll
        for (int r = 0; r < 4; ++r) {
            int row = m0 + quad * 4 + r;
            float v = fmaxf(acc[nt][r] + bv, 0.f);
            if constexpr (OUTF) ((float*)out_)[(size_t)row * 128 + col] = v;
            else                ((u16*)out_)[(size_t)row * 128 + col] = f2bf(v);
        }
    }
}

// ---------------- paired classifier + risk heads (fallback path only) ----------------
struct HeadJob {
    const float* X; const u16* W1p;
    const float* b1a; const float* b1b;
    const float* cW2; const float* cb2;
    const float* rW2; const float* rb2;
    float* pred; float* risk; int M; int nBlk;
};

__global__ void __launch_bounds__(256) head_pair(HeadJob h0, HeadJob h1) {
    __shared__ alignas(16) u16 lds[4][16][128 + LDS_PAD];
    const bool second = (int)blockIdx.x >= h0.nBlk;
    const HeadJob& h = second ? h1 : h0;
    const int bx = second ? blockIdx.x - h0.nBlk : blockIdx.x;
    const int lane = threadIdx.x & 63;
    const int wv = threadIdx.x >> 6;
    const int m0 = (bx * 4 + wv) * 16;
    const bool active = (m0 < h.M);
    const int quad = lane >> 4;
    const int l15 = lane & 15;

    if (active) {
        f32x4 acc[8];
#pragma unroll
        for (int i = 0; i < 8; ++i) acc[i] = (f32x4){0.f, 0.f, 0.f, 0.f};
#pragma unroll
        for (int kt = 0; kt < 4; ++kt) {
            bf16x8 a = cvt8(h.X + (size_t)(m0 + l15) * 128 + kt * 32 + quad * 8);
#pragma unroll
            for (int nt = 0; nt < 8; ++nt) {
                bf16x8 b = *reinterpret_cast<const bf16x8*>(h.W1p + (size_t)(((kt * 8 + nt) * 64 + lane) * 8));
                acc[nt] = __builtin_amdgcn_mfma_f32_16x16x32_bf16(a, b, acc[nt], 0, 0, 0);
            }
        }
#pragma unroll
        for (int nt = 0; nt < 8; ++nt) {
            int col = nt * 16 + l15;
            float bv = (col < 64) ? h.b1a[col] : h.b1b[col - 64];
#pragma unroll
            for (int r = 0; r < 4; ++r) {
                float v = fmaxf(acc[nt][r] + bv, 0.f);
                lds[wv][quad * 4 + r][col] = f2bf(v);
            }
        }
    }
    __syncthreads();
    if (!active) return;

    float w0 = h.cW2[lane * 2 + 0];
    float w1 = h.cW2[lane * 2 + 1];
    float w2 = h.rW2[lane];
    float cb0 = h.cb2[0], cb1v = h.cb2[1], rb = h.rb2[0];
    for (int r = 0; r < 16; ++r) {
        float t1 = bf2f(lds[wv][r][lane]);
        float t2 = bf2f(lds[wv][r][64 + lane]);
        float s0 = t1 * w0;
        float s1 = t1 * w1;
        float s2 = t2 * w2;
        for (int off = 32; off > 0; off >>= 1) {
            s0 += __shfl_xor(s0, off);
            s1 += __shfl_xor(s1, off);
            s2 += __shfl_xor(s2, off);
        }
        if (lane == 0) {
            int row = m0 + r;
            h.pred[(size_t)row * 2 + 0] = s0 + cb0;
            h.pred[(size_t)row * 2 + 1] = s1 + cb1v;
            float z = s2 + rb;
            h.risk[row] = 1.f / (1.f + __expf(-z));
        }
    }
}

// ---------------- host ----------------
// tight layout (bytes); all offsets 16B-aligned
#define OFF_CNT_M  ((size_t)0)          // 50000*32  = 1,600,000
#define OFF_CNT_C  ((size_t)1600000)    // 100000*32 = 3,200,000 -> ends 4,800,000
#define OFF_BKT_M  ((size_t)4800000)    // 50000*64*4 = 12,800,000 -> ends 17,600,000
#define OFF_BKT_C  ((size_t)17600000)   // 100000*64*2 = 12,800,000 -> ends 30,400,000
#define OFF_HM     ((size_t)30400000)   // (50000*128+128)*2 = 12,800,256 -> ends 43,200,256
#define OFF_PACK   ((size_t)43200256)   // 10*32768 = 327,680 -> ends 43,527,936
#define OFF_XC     ((size_t)43527936)   // (100000*64+64)*2 = 12,800,128 -> ends 56,328,064
#define OFF_XM     ((size_t)56328192)   // (50000*64+64)*2 = 6,400,128 -> ends 62,728,320
#define OFF_HCB    ((size_t)62728448)   // (100000*128+128)*2 = 25,600,256 -> ends 88,328,704
#define WS_SHADOW_NEED ((size_t)89000000)   // < proven-available 91.2e6 (87 MiB)

extern "C" void kernel_launch(void* const* d_in, const int* in_sizes, int n_in,
                              void* d_out, int out_size, void* d_ws, size_t ws_size,
                              hipStream_t stream)
{
    const float* x_card   = (const float*)d_in[0];
    const float* x_merch  = (const float*)d_in[1];
    const int* src_cm     = (const int*)d_in[2];
    const int* dst_cm     = (const int*)d_in[3];
    const int* src_mc     = (const int*)d_in[4];
    const int* dst_mc     = (const int*)d_in[5];
    const float* Wl0_cm   = (const float*)d_in[6];
    const float* bl0_cm   = (const float*)d_in[7];
    const float* Wr0_cm   = (const float*)d_in[8];
    const float* Wl0_mc   = (const float*)d_in[9];
    const float* bl0_mc   = (const float*)d_in[10];
    const float* Wr0_mc   = (const float*)d_in[11];
    const float* Wl1_cm   = (const float*)d_in[12];
    const float* bl1_cm   = (const float*)d_in[13];
    const float* Wr1_cm   = (const float*)d_in[14];
    const float* Wl1_mc   = (const float*)d_in[15];
    const float* bl1_mc   = (const float*)d_in[16];
    const float* Wr1_mc   = (const float*)d_in[17];
    const float* cW1_card = (const float*)d_in[18];
    const float* cb1_card = (const float*)d_in[19];
    const float* cW2_card = (const float*)d_in[20];
    const float* cb2_card = (const float*)d_in[21];
    const float* cW1_mer  = (const float*)d_in[22];
    const float* cb1_mer  = (const float*)d_in[23];
    const float* cW2_mer  = (const float*)d_in[24];
    const float* cb2_mer  = (const float*)d_in[25];
    const float* rW1      = (const float*)d_in[26];
    const float* rb1      = (const float*)d_in[27];
    const float* rW2      = (const float*)d_in[28];
    const float* rb2      = (const float*)d_in[29];

    const int nCard  = in_sizes[0] / 64;   // 100000
    const int nMerch = in_sizes[1] / 64;   // 50000
    const int E      = in_sizes[2];        // 1000000

    char* ws = (char*)d_ws;
    int* cnt_m    = (int*)(ws + OFF_CNT_M);
    int* cnt_c    = (int*)(ws + OFF_CNT_C);
    u32* bucket_m = (u32*)(ws + OFF_BKT_M);
    u16* bucket_c = (u16*)(ws + OFF_BKT_C);
    u16* h_m      = (u16*)(ws + OFF_HM);
    u16* pw       = (u16*)(ws + OFF_PACK);
    u16* pWl0_cm = pw + 0 * 16384;
    u16* pWr0_cm = pw + 1 * 16384;
    u16* pWl0_mc = pw + 2 * 16384;
    u16* pWr0_mc = pw + 3 * 16384;
    u16* pWl1_cm = pw + 4 * 16384;
    u16* pWr1_cm = pw + 5 * 16384;
    u16* pWl1_mc = pw + 6 * 16384;
    u16* pWr1_mc = pw + 7 * 16384;
    u16* pHeadC  = pw + 8 * 16384;
    u16* pHeadM  = pw + 9 * 16384;
    u16* xc_bf   = (u16*)(ws + OFF_XC);
    u16* xm_bf   = (u16*)(ws + OFF_XM);
    u16* hc_bf   = (u16*)(ws + OFF_HCB);

    const bool shadow = (ws_size >= WS_SHADOW_NEED);

    float* out     = (float*)d_out;
    float* o_hc2   = out;
    float* o_hm2   = o_hc2 + (size_t)nCard * 128;
    float* o_predc = o_hm2 + (size_t)nMerch * 128;
    float* o_predm = o_predc + (size_t)nCard * 2;
    float* o_riskc = o_predm + (size_t)nMerch * 2;
    float* o_riskm = o_riskc + (size_t)nCard;

    // zero the padded count arrays (build uses global atomicAdd)
    hipMemsetAsync(ws, 0, (size_t)(nMerch + nCard) * CSTRIDE * sizeof(int), stream);

    // ---- prep: build + pack (+ converts + zero-rows when shadow) ----
    PrepArgs pa;
    pa.src_cm = src_cm; pa.dst_cm = dst_cm; pa.src_mc = src_mc; pa.dst_mc = dst_mc;
    pa.cnt_m = cnt_m; pa.bucket_m = bucket_m; pa.cnt_c = cnt_c; pa.bucket_c = bucket_c;
    pa.E = E; pa.nMerch = nMerch; pa.nCard = nCard;
    pa.xc = x_card;  pa.xcb = xc_bf; pa.ncBlk = shadow ? ((nCard * 64 + 4095) / 4096) : 0;   // 1563
    pa.xm = x_merch; pa.xmb = xm_bf; pa.nmBlk = shadow ? ((nMerch * 64 + 4095) / 4096) : 0;  // 782
    pa.hmz = h_m + (size_t)nMerch * 128;
    pa.hcz = hc_bf + (size_t)nCard * 128;
    pa.pd[0]  = { Wl0_cm,   pWl0_cm,  64, 128, 0 };
    pa.pd[1]  = { Wr0_cm,   pWr0_cm,  64, 128, 0 };
    pa.pd[2]  = { Wl0_mc,   pWl0_mc,  64, 128, 0 };
    pa.pd[3]  = { Wr0_mc,   pWr0_mc,  64, 128, 0 };
    pa.pd[4]  = { Wl1_cm,   pWl1_cm, 128, 128, 0 };
    pa.pd[5]  = { Wr1_cm,   pWr1_cm, 128, 128, 0 };
    pa.pd[6]  = { Wl1_mc,   pWl1_mc, 128, 128, 0 };
    pa.pd[7]  = { Wr1_mc,   pWr1_mc, 128, 128, 0 };
    pa.pd[8]  = { cW1_card, pHeadC,  128,  64, 0 };
    pa.pd[9]  = { rW1,      pHeadC,  128,  64, 4 };
    pa.pd[10] = { cW1_mer,  pHeadM,  128,  64, 0 };
    pa.pd[11] = { rW1,      pHeadM,  128,  64, 4 };
    int prepGrid = NBUILD + NPACK + pa.ncBlk + pa.nmBlk + (shadow ? 1 : 0);
    prep<<<prepGrid, 256, 0, stream>>>(pa);

    if (shadow) {
        const int nbM = (nMerch + 63) / 64;   // 782
        const int nbC = (nCard + 63) / 64;    // 1563

        // ---- layer 0 pair (no heads; layer-1 overwrites o_hc2, so no fp32 store) ----
        SageJob a0 = { xc_bf, bucket_m, cnt_m, pWl0_cm, xm_bf, pWr0_cm, bl0_cm,
                       nullptr, h_m, nullptr, nMerch, 1, nbM, nCard,
                       nullptr, nullptr, nullptr, nullptr, nullptr, nullptr, nullptr,
                       nullptr, nullptr };
        SageJob a1 = { xm_bf, bucket_c, cnt_c, pWl0_mc, xc_bf, pWr0_mc, bl0_mc,
                       nullptr, nullptr, hc_bf, nCard, 0, nbC, nMerch,
                       nullptr, nullptr, nullptr, nullptr, nullptr, nullptr, nullptr,
                       nullptr, nullptr };
        sage_pair<64><<<nbM + nbC, 256, 0, stream>>>(a0, a1);

        // ---- layer 1 pair + fused heads ----
        SageJob b0 = { hc_bf, bucket_m, cnt_m, pWl1_cm, h_m, pWr1_cm, bl1_cm,
                       o_hm2, nullptr, nullptr, nMerch, 1, nbM, nCard,
                       pHeadM, cb1_mer, rb1, cW2_mer, cb2_mer, rW2, rb2,
                       o_predm, o_riskm };
        SageJob b1 = { h_m, bucket_c, cnt_c, pWl1_mc, hc_bf, pWr1_mc, bl1_mc,
                       o_hc2, nullptr, nullptr, nCard, 0, nbC, nMerch,
                       pHeadC, cb1_card, rb1, cW2_card, cb2_card, rW2, rb2,
                       o_predc, o_riskc };
        sage_pair<128><<<nbM + nbC, 256, 0, stream>>>(b0, b1);
    } else {
        const int nbM = (nMerch + 63) / 64;   // 782
        const int nbC = (nCard + 63) / 64;    // 1563
        // fallback: fp32 gathers, in-place h_c update (row-disjoint)
        sage_fused<u32, 64, true, true, false><<<nbM, 256, 0, stream>>>(
            x_card, bucket_m, cnt_m, pWl0_cm, x_merch, pWr0_cm, bl0_cm, h_m, nMerch);
        sage_fused<u16, 64, true, true, true><<<nbC, 256, 0, stream>>>(
            x_merch, bucket_c, cnt_c, pWl0_mc, x_card, pWr0_mc, bl0_mc, o_hc2, nCard);
        sage_fused<u32, 128, true, false, true><<<nbM, 256, 0, stream>>>(
            o_hc2, bucket_m, cnt_m, pWl1_cm, h_m, pWr1_cm, bl1_cm, o_hm2, nMerch);
        sage_fused<u16, 128, false, true, true><<<nbC, 256, 0, stream>>>(
            h_m, bucket_c, cnt_c, pWl1_mc, o_hc2, pWr1_mc, bl1_mc, o_hc2, nCard);

        HeadJob hc = { o_hc2, pHeadC, cb1_card, rb1, cW2_card, cb2_card, rW2, rb2,
                       o_predc, o_riskc, nCard, nbC };
        HeadJob hm = { o_hm2, pHeadM, cb1_mer, rb1, cW2_mer, cb2_mer, rW2, rb2,
                       o_predm, o_riskm, nMerch, nbM };
        head_pair<<<nbC + nbM, 256, 0, stream>>>(hc, hm);
    }
}